// Round 1
// baseline (716.234 us; speedup 1.0000x reference)
//
#include <hip/hip_runtime.h>

// B=8, N=256, H=256
// Inputs: x (8,256,256) f32, edge_gate (8,256,256,256) f32,
//         U_w (256,256), U_b (256), V_w (256,256), V_b (256)
// Out: (8,256,256) f32
//
// C workspace layout: C[m][n], m in [0,2048) = b*256+row, n in [0,512):
//   n <  256 -> Ux[m][n]
//   n >= 256 -> Vx[m][n-256]

#define LDS_STRIDE 72  // 64 + 8 pad: keeps float4 alignment, ~2-way write conflicts max

__global__ __launch_bounds__(256) void gemm_uv(
    const float* __restrict__ x, const float* __restrict__ U_w,
    const float* __restrict__ U_b, const float* __restrict__ V_w,
    const float* __restrict__ V_b, float* __restrict__ C) {
  __shared__ float Xs[32 * LDS_STRIDE];
  __shared__ float Ws[32 * LDS_STRIDE];
  const int t  = threadIdx.x;
  const int gx = blockIdx.x;   // n-tile: 0..7
  const int gy = blockIdx.y;   // m-tile: 0..31
  const int n0 = gx * 64;
  const int m0 = gy * 64;
  // gx<4 -> all columns in U; gx>=4 -> all in V (uniform per block)
  const float* Wsrc  = (gx < 4) ? U_w : V_w;
  const float* bsrc  = (gx < 4) ? U_b : V_b;
  const int    nbase = (gx < 4) ? n0  : n0 - 256;
  const int tn = t & 15;
  const int tm = t >> 4;
  float acc[4][4] = {};

  for (int k0 = 0; k0 < 256; k0 += 32) {
    // stage 64x32 tiles of X and W' (transposed into LDS: [k][m])
    #pragma unroll
    for (int rep = 0; rep < 2; ++rep) {
      const int f  = t + rep * 256;   // 0..511
      const int rl = f >> 3;          // row in tile: 0..63
      const int h4 = f & 7;           // float4 col: 0..7 (32 cols)
      float4 xa = *(const float4*)(x    + (m0    + rl) * 256 + k0 + h4 * 4);
      float4 wa = *(const float4*)(Wsrc + (nbase + rl) * 256 + k0 + h4 * 4);
      Xs[(h4 * 4 + 0) * LDS_STRIDE + rl] = xa.x;
      Xs[(h4 * 4 + 1) * LDS_STRIDE + rl] = xa.y;
      Xs[(h4 * 4 + 2) * LDS_STRIDE + rl] = xa.z;
      Xs[(h4 * 4 + 3) * LDS_STRIDE + rl] = xa.w;
      Ws[(h4 * 4 + 0) * LDS_STRIDE + rl] = wa.x;
      Ws[(h4 * 4 + 1) * LDS_STRIDE + rl] = wa.y;
      Ws[(h4 * 4 + 2) * LDS_STRIDE + rl] = wa.z;
      Ws[(h4 * 4 + 3) * LDS_STRIDE + rl] = wa.w;
    }
    __syncthreads();
    #pragma unroll
    for (int kk = 0; kk < 32; ++kk) {
      float4 a = *(const float4*)(&Xs[kk * LDS_STRIDE + tm * 4]);
      float4 b = *(const float4*)(&Ws[kk * LDS_STRIDE + tn * 4]);
      float av[4] = {a.x, a.y, a.z, a.w};
      float bv[4] = {b.x, b.y, b.z, b.w};
      #pragma unroll
      for (int i = 0; i < 4; ++i)
        #pragma unroll
        for (int j = 0; j < 4; ++j)
          acc[i][j] += av[i] * bv[j];
    }
    __syncthreads();
  }

  const float4 bias = *(const float4*)(bsrc + nbase + tn * 4);
  const float bv[4] = {bias.x, bias.y, bias.z, bias.w};
  #pragma unroll
  for (int i = 0; i < 4; ++i) {
    float4 o;
    o.x = acc[i][0] + bv[0];
    o.y = acc[i][1] + bv[1];
    o.z = acc[i][2] + bv[2];
    o.w = acc[i][3] + bv[3];
    *(float4*)(C + (m0 + tm * 4 + i) * 512 + n0 + tn * 4) = o;
  }
}

// One block per (b,i). 4 waves; wave g handles j = g, g+4, ...
// Lane within wave holds h-channels [4*h4, 4*h4+4).
__global__ __launch_bounds__(256) void fuse_gate(
    const float* __restrict__ eg, const float* __restrict__ C,
    float* __restrict__ out) {
  const int i  = blockIdx.x;   // 0..255
  const int b  = blockIdx.y;   // 0..7
  const int t  = threadIdx.x;
  const int h4 = t & 63;
  const int jg = t >> 6;

  const float4* eg4 = (const float4*)eg;
  const float4* C4  = (const float4*)C;

  const int row_bi = b * 256 + i;
  const int eg_base = row_bi * (256 * 64);     // float4 units; + j*64 + h4
  const int vx_base = b * 256 * 128 + 64;      // C4 row stride 128; Vx at +64

  float4 num = {0.f, 0.f, 0.f, 0.f};
  float4 den = {0.f, 0.f, 0.f, 0.f};
  for (int j = jg; j < 256; j += 4) {
    float4 e = eg4[eg_base + j * 64 + h4];
    float4 v = C4[vx_base + j * 128 + h4];
    num.x += e.x * v.x;  num.y += e.y * v.y;
    num.z += e.z * v.z;  num.w += e.w * v.w;
    den.x += e.x;  den.y += e.y;
    den.z += e.z;  den.w += e.w;
  }

  __shared__ float4 nsh[256];
  __shared__ float4 dsh[256];
  nsh[t] = num;
  dsh[t] = den;
  __syncthreads();

  if (t < 64) {
    float4 ns = nsh[t];
    float4 ds = dsh[t];
    #pragma unroll
    for (int g = 1; g < 4; ++g) {
      float4 nn = nsh[g * 64 + t];
      float4 dd = dsh[g * 64 + t];
      ns.x += nn.x; ns.y += nn.y; ns.z += nn.z; ns.w += nn.w;
      ds.x += dd.x; ds.y += dd.y; ds.z += dd.z; ds.w += dd.w;
    }
    float4 u = C4[row_bi * 128 + t];  // Ux part (cols 0..255)
    float4 o;
    o.x = u.x + ns.x / (1e-20f + ds.x);
    o.y = u.y + ns.y / (1e-20f + ds.y);
    o.z = u.z + ns.z / (1e-20f + ds.z);
    o.w = u.w + ns.w / (1e-20f + ds.w);
    ((float4*)out)[row_bi * 64 + t] = o;
  }
}

extern "C" void kernel_launch(void* const* d_in, const int* in_sizes, int n_in,
                              void* d_out, int out_size, void* d_ws, size_t ws_size,
                              hipStream_t stream) {
  const float* x   = (const float*)d_in[0];
  const float* eg  = (const float*)d_in[1];
  const float* U_w = (const float*)d_in[2];
  const float* U_b = (const float*)d_in[3];
  const float* V_w = (const float*)d_in[4];
  const float* V_b = (const float*)d_in[5];
  float* out = (float*)d_out;
  float* C   = (float*)d_ws;  // needs 2048*512*4 = 4 MB

  gemm_uv<<<dim3(8, 32), 256, 0, stream>>>(x, U_w, U_b, V_w, V_b, C);
  fuse_gate<<<dim3(256, 8), 256, 0, stream>>>(eg, C, out);
}

// Round 2
// 686.608 us; speedup vs baseline: 1.0431x; 1.0431x over previous
//
#include <hip/hip_runtime.h>

// B=8, N=256, H=256
// out[b,i,h] = Ux[b,i,h] + (sum_j eg[b,i,j,h]*Vx[b,j,h]) / (1e-20 + sum_j eg[b,i,j,h])
// Ux is written directly to d_out by the GEMM; Vx (2 MB) lives in d_ws.

typedef float f4 __attribute__((ext_vector_type(4)));
typedef float f2 __attribute__((ext_vector_type(2)));

#define S36 36  // 32 k-floats + 4 pad: keeps 16B alignment, <=4-way read conflicts

__global__ __launch_bounds__(256) void gemm_uv(
    const float* __restrict__ x, const float* __restrict__ U_w,
    const float* __restrict__ U_b, const float* __restrict__ V_w,
    const float* __restrict__ V_b, float* __restrict__ Ux,
    float* __restrict__ Vx) {
  __shared__ float Xs[64 * S36];   // [m][k] 64x32
  __shared__ float Ws[32 * S36];   // [n][k] 32x32
  const int t  = threadIdx.x;
  const int gx = blockIdx.x;   // 0..15: n-tile (32 wide); gx<8 -> U, else V
  const int gy = blockIdx.y;   // 0..31: m-tile (64)
  const int m0 = gy * 64;
  const bool isU = (gx < 8);
  const float* Wsrc = isU ? U_w : V_w;
  const float* bsrc = isU ? U_b : V_b;
  const int n0 = (gx & 7) * 32;
  float* dst = isU ? Ux : Vx;

  const int tn = t & 15;   // n = 2*tn .. +1
  const int tm = t >> 4;   // m = 4*tm .. +3
  float acc[4][2] = {};

  const int lm = t >> 3;   // 0..31
  const int lc = t & 7;    // f4 index along k

  for (int k0 = 0; k0 < 256; k0 += 32) {
    #pragma unroll
    for (int r = 0; r < 2; ++r) {
      const int m = r * 32 + lm;
      f4 v = *(const f4*)(x + (m0 + m) * 256 + k0 + lc * 4);
      *(f4*)(&Xs[m * S36 + lc * 4]) = v;
    }
    {
      f4 v = *(const f4*)(Wsrc + (n0 + lm) * 256 + k0 + lc * 4);
      *(f4*)(&Ws[lm * S36 + lc * 4]) = v;
    }
    __syncthreads();
    #pragma unroll
    for (int kq = 0; kq < 8; ++kq) {
      f4 a0 = *(const f4*)(&Xs[(tm * 4 + 0) * S36 + kq * 4]);
      f4 a1 = *(const f4*)(&Xs[(tm * 4 + 1) * S36 + kq * 4]);
      f4 a2 = *(const f4*)(&Xs[(tm * 4 + 2) * S36 + kq * 4]);
      f4 a3 = *(const f4*)(&Xs[(tm * 4 + 3) * S36 + kq * 4]);
      f4 b0 = *(const f4*)(&Ws[(tn * 2 + 0) * S36 + kq * 4]);
      f4 b1 = *(const f4*)(&Ws[(tn * 2 + 1) * S36 + kq * 4]);
      acc[0][0] += a0.x*b0.x + a0.y*b0.y + a0.z*b0.z + a0.w*b0.w;
      acc[0][1] += a0.x*b1.x + a0.y*b1.y + a0.z*b1.z + a0.w*b1.w;
      acc[1][0] += a1.x*b0.x + a1.y*b0.y + a1.z*b0.z + a1.w*b0.w;
      acc[1][1] += a1.x*b1.x + a1.y*b1.y + a1.z*b1.z + a1.w*b1.w;
      acc[2][0] += a2.x*b0.x + a2.y*b0.y + a2.z*b0.z + a2.w*b0.w;
      acc[2][1] += a2.x*b1.x + a2.y*b1.y + a2.z*b1.z + a2.w*b1.w;
      acc[3][0] += a3.x*b0.x + a3.y*b0.y + a3.z*b0.z + a3.w*b0.w;
      acc[3][1] += a3.x*b1.x + a3.y*b1.y + a3.z*b1.z + a3.w*b1.w;
    }
    __syncthreads();
  }

  const float bb0 = bsrc[n0 + 2 * tn + 0];
  const float bb1 = bsrc[n0 + 2 * tn + 1];
  #pragma unroll
  for (int i = 0; i < 4; ++i) {
    f2 o;
    o.x = acc[i][0] + bb0;
    o.y = acc[i][1] + bb1;
    *(f2*)(dst + (m0 + 4 * tm + i) * 256 + n0 + 2 * tn) = o;
  }
}

// One block per (b,i). 4 waves; wave g handles j = g, g+4, ...
__global__ __launch_bounds__(256) void fuse_gate(
    const float* __restrict__ eg, const float* __restrict__ Vx,
    float* __restrict__ out) {
  const int i  = blockIdx.x;   // 0..255
  const int b  = blockIdx.y;   // 0..7
  const int t  = threadIdx.x;
  const int h4 = t & 63;
  const int jg = t >> 6;

  const f4* eg4 = (const f4*)eg;
  const f4* vx4 = (const f4*)Vx;
  const int row = b * 256 + i;
  const int egb = row * (256 * 64);   // f4 units
  const int vxb = b * (256 * 64);

  f4 num = {0.f, 0.f, 0.f, 0.f};
  f4 den = {0.f, 0.f, 0.f, 0.f};
  #pragma unroll 4
  for (int j = jg; j < 256; j += 4) {
    f4 e = __builtin_nontemporal_load(&eg4[egb + j * 64 + h4]);
    f4 v = vx4[vxb + j * 64 + h4];
    num += e * v;
    den += e;
  }

  __shared__ f4 nsh[256];
  __shared__ f4 dsh[256];
  nsh[t] = num;
  dsh[t] = den;
  __syncthreads();

  if (t < 64) {
    f4 ns = nsh[t];
    f4 ds = dsh[t];
    #pragma unroll
    for (int g = 1; g < 4; ++g) { ns += nsh[g * 64 + t]; ds += dsh[g * 64 + t]; }
    f4 u = ((const f4*)out)[row * 64 + t];
    f4 eps = {1e-20f, 1e-20f, 1e-20f, 1e-20f};
    f4 o = u + ns / (eps + ds);
    ((f4*)out)[row * 64 + t] = o;
  }
}

extern "C" void kernel_launch(void* const* d_in, const int* in_sizes, int n_in,
                              void* d_out, int out_size, void* d_ws, size_t ws_size,
                              hipStream_t stream) {
  const float* x   = (const float*)d_in[0];
  const float* eg  = (const float*)d_in[1];
  const float* U_w = (const float*)d_in[2];
  const float* U_b = (const float*)d_in[3];
  const float* V_w = (const float*)d_in[4];
  const float* V_b = (const float*)d_in[5];
  float* out = (float*)d_out;
  float* Vx  = (float*)d_ws;  // 2048*256*4 = 2 MB

  gemm_uv<<<dim3(16, 32), 256, 0, stream>>>(x, U_w, U_b, V_w, V_b, out, Vx);
  fuse_gate<<<dim3(256, 8), 256, 0, stream>>>(eg, Vx, out);
}

// Round 3
// 685.246 us; speedup vs baseline: 1.0452x; 1.0020x over previous
//
#include <hip/hip_runtime.h>

// B=8, N=256, H=256
// out[b,i,h] = Ux[b,i,h] + (sum_j eg[b,i,j,h]*Vx[b,j,h]) / (1e-20 + sum_j eg[b,i,j,h])
// Ux is written directly to d_out by the GEMM; Vx (2 MB) lives in d_ws.

typedef float f4 __attribute__((ext_vector_type(4)));
typedef float f2 __attribute__((ext_vector_type(2)));

#define S36 36  // 32 k-floats + 4 pad: keeps 16B alignment, <=4-way read conflicts

__global__ __launch_bounds__(256) void gemm_uv(
    const float* __restrict__ x, const float* __restrict__ U_w,
    const float* __restrict__ U_b, const float* __restrict__ V_w,
    const float* __restrict__ V_b, float* __restrict__ Ux,
    float* __restrict__ Vx) {
  __shared__ float Xs[64 * S36];   // [m][k] 64x32
  __shared__ float Ws[32 * S36];   // [n][k] 32x32
  const int t  = threadIdx.x;
  const int gx = blockIdx.x;   // 0..15: n-tile (32 wide); gx<8 -> U, else V
  const int gy = blockIdx.y;   // 0..31: m-tile (64)
  const int m0 = gy * 64;
  const bool isU = (gx < 8);
  const float* Wsrc = isU ? U_w : V_w;
  const float* bsrc = isU ? U_b : V_b;
  const int n0 = (gx & 7) * 32;
  float* dst = isU ? Ux : Vx;

  const int tn = t & 15;   // n = 2*tn .. +1
  const int tm = t >> 4;   // m = 4*tm .. +3
  float acc[4][2] = {};

  const int lm = t >> 3;   // 0..31
  const int lc = t & 7;    // f4 index along k

  for (int k0 = 0; k0 < 256; k0 += 32) {
    #pragma unroll
    for (int r = 0; r < 2; ++r) {
      const int m = r * 32 + lm;
      f4 v = *(const f4*)(x + (m0 + m) * 256 + k0 + lc * 4);
      *(f4*)(&Xs[m * S36 + lc * 4]) = v;
    }
    {
      f4 v = *(const f4*)(Wsrc + (n0 + lm) * 256 + k0 + lc * 4);
      *(f4*)(&Ws[lm * S36 + lc * 4]) = v;
    }
    __syncthreads();
    #pragma unroll
    for (int kq = 0; kq < 8; ++kq) {
      f4 a0 = *(const f4*)(&Xs[(tm * 4 + 0) * S36 + kq * 4]);
      f4 a1 = *(const f4*)(&Xs[(tm * 4 + 1) * S36 + kq * 4]);
      f4 a2 = *(const f4*)(&Xs[(tm * 4 + 2) * S36 + kq * 4]);
      f4 a3 = *(const f4*)(&Xs[(tm * 4 + 3) * S36 + kq * 4]);
      f4 b0 = *(const f4*)(&Ws[(tn * 2 + 0) * S36 + kq * 4]);
      f4 b1 = *(const f4*)(&Ws[(tn * 2 + 1) * S36 + kq * 4]);
      acc[0][0] += a0.x*b0.x + a0.y*b0.y + a0.z*b0.z + a0.w*b0.w;
      acc[0][1] += a0.x*b1.x + a0.y*b1.y + a0.z*b1.z + a0.w*b1.w;
      acc[1][0] += a1.x*b0.x + a1.y*b0.y + a1.z*b0.z + a1.w*b0.w;
      acc[1][1] += a1.x*b1.x + a1.y*b1.y + a1.z*b1.z + a1.w*b1.w;
      acc[2][0] += a2.x*b0.x + a2.y*b0.y + a2.z*b0.z + a2.w*b0.w;
      acc[2][1] += a2.x*b1.x + a2.y*b1.y + a2.z*b1.z + a2.w*b1.w;
      acc[3][0] += a3.x*b0.x + a3.y*b0.y + a3.z*b0.z + a3.w*b0.w;
      acc[3][1] += a3.x*b1.x + a3.y*b1.y + a3.z*b1.z + a3.w*b1.w;
    }
    __syncthreads();
  }

  const float bb0 = bsrc[n0 + 2 * tn + 0];
  const float bb1 = bsrc[n0 + 2 * tn + 1];
  #pragma unroll
  for (int i = 0; i < 4; ++i) {
    f2 o;
    o.x = acc[i][0] + bb0;
    o.y = acc[i][1] + bb1;
    *(f2*)(dst + (m0 + 4 * tm + i) * 256 + n0 + 2 * tn) = o;
  }
}

// One block per (b,i). 4 waves; wave g handles j = g, g+4, ...
// launch_bounds(256,4): allow up to ~128 VGPR so the unroll-8 load batch
// (16 loads in flight/lane) doesn't spill; 16 waves/CU is still far more
// outstanding-load coverage than the ~9KB/CU needed at 900cyc HBM latency.
__global__ __launch_bounds__(256, 4) void fuse_gate(
    const float* __restrict__ eg, const float* __restrict__ Vx,
    float* __restrict__ out) {
  const int i  = blockIdx.x;   // 0..255
  const int b  = blockIdx.y;   // 0..7
  const int t  = threadIdx.x;
  const int h4 = t & 63;
  const int jg = t >> 6;

  const f4* eg4 = (const f4*)eg;
  const f4* vx4 = (const f4*)Vx;
  const int row = b * 256 + i;
  const int egb = row * (256 * 64);   // f4 units
  const int vxb = b * (256 * 64);

  f4 num = {0.f, 0.f, 0.f, 0.f};
  f4 den = {0.f, 0.f, 0.f, 0.f};
  #pragma unroll 8
  for (int j = jg; j < 256; j += 4) {
    f4 e = __builtin_nontemporal_load(&eg4[egb + j * 64 + h4]);
    f4 v = vx4[vxb + j * 64 + h4];
    num += e * v;
    den += e;
  }

  __shared__ f4 nsh[256];
  __shared__ f4 dsh[256];
  nsh[t] = num;
  dsh[t] = den;
  __syncthreads();

  if (t < 64) {
    f4 ns = nsh[t];
    f4 ds = dsh[t];
    #pragma unroll
    for (int g = 1; g < 4; ++g) { ns += nsh[g * 64 + t]; ds += dsh[g * 64 + t]; }
    f4 u = ((const f4*)out)[row * 64 + t];
    f4 eps = {1e-20f, 1e-20f, 1e-20f, 1e-20f};
    f4 o = u + ns / (eps + ds);
    ((f4*)out)[row * 64 + t] = o;
  }
}

extern "C" void kernel_launch(void* const* d_in, const int* in_sizes, int n_in,
                              void* d_out, int out_size, void* d_ws, size_t ws_size,
                              hipStream_t stream) {
  const float* x   = (const float*)d_in[0];
  const float* eg  = (const float*)d_in[1];
  const float* U_w = (const float*)d_in[2];
  const float* U_b = (const float*)d_in[3];
  const float* V_w = (const float*)d_in[4];
  const float* V_b = (const float*)d_in[5];
  float* out = (float*)d_out;
  float* Vx  = (float*)d_ws;  // 2048*256*4 = 2 MB

  gemm_uv<<<dim3(16, 32), 256, 0, stream>>>(x, U_w, U_b, V_w, V_b, out, Vx);
  fuse_gate<<<dim3(256, 8), 256, 0, stream>>>(eg, Vx, out);
}